// Round 10
// baseline (55.585 us; speedup 1.0000x reference)
//
#include <hip/hip_runtime.h>

// TemporalDenoise: bidirectional per-channel EMA, averaged.
// R10 = R9 (LDS-free register scan + wave-local shuffle carry propagation)
// with ONE structural change: 4-wave (256-thread) blocks.
//  - R9's 1-wave blocks hit the per-CU workgroup-slot limit (~16): occupancy
//    pinned at 41% (~13 waves/CU) with VGPR=48 imposing no cap. 4-wave blocks
//    raise the WG-slot-implied wave ceiling 4x.
//  - Each block covers 4 adjacent channel tiles (cgt quad) of one time tile:
//    waves fetch contiguous 512B-wide stripes -> L2 spatial locality.
//  - Carry math unchanged: F = t1 + d8*(t2 + d8*(t3 + d8*t4)), truncation
//    err d8^4 ~ 1e-5; wave-edge histories = 16 clamped steps (exact at
//    t=0/t=T-1); all shuffles wave-local (lane = tid & 63).
// Plain stores (nt stores cost +25% WRITE_SIZE, R3).

#define BB 32
#define TT 2048
#define CGALL 128           // f32x4 groups per (b,t) row (512 ch)
#define CGT 8               // f32x4 groups per wave = 32 ch
#define NCGT (CGALL / CGT)  // 16
#define NCGQ (NCGT / 4)     // 4 channel quads (4 waves/block)
#define LCH 8               // time steps per thread
#define NCHW 8              // chunks per wave
#define TB (LCH * NCHW)     // 64 time steps per wave tile
#define NTB (TT / TB)       // 32
#define HALO 16

typedef float f32x4 __attribute__((ext_vector_type(4)));

static __device__ __forceinline__ f32x4 fma4(const f32x4 a, const f32x4 b,
                                             const f32x4 c) {
  f32x4 r;
  r.x = fmaf(a.x, b.x, c.x);
  r.y = fmaf(a.y, b.y, c.y);
  r.z = fmaf(a.z, b.z, c.z);
  r.w = fmaf(a.w, b.w, c.w);
  return r;
}

static __device__ __forceinline__ f32x4 shfl4(const f32x4 v, int srcLane) {
  const int s = srcLane & 63;  // wave-local
  f32x4 r;
  r.x = __shfl(v.x, s, 64);
  r.y = __shfl(v.y, s, 64);
  r.z = __shfl(v.z, s, 64);
  r.w = __shfl(v.w, s, 64);
  return r;
}

__global__ __launch_bounds__(256, 4) void ema_bidir_kernel(
    const f32x4* __restrict__ x, const f32x4* __restrict__ alogit4,
    f32x4* __restrict__ out) {
  const int bid = blockIdx.x;
  const int cgq = bid & (NCGQ - 1);       // channel quad (fastest)
  const int tb = (bid >> 2) & (NTB - 1);  // time tile
  const int b = bid >> 7;                 // batch

  const int w = threadIdx.x >> 6;   // wave in block (0..3)
  const int lane = threadIdx.x & 63;
  const int cgi = lane & 7;         // channel group within wave tile
  const int ch = lane >> 3;         // chunk within wave (0..7)

  const int cgt = cgq * 4 + w;      // this wave's channel tile
  const int t0w = tb * TB;          // wave tile start
  const int t0 = t0w + ch * LCH;    // chunk start

  const f32x4* xr = x + ((size_t)b * TT) * CGALL + cgt * CGT + cgi;
  f32x4* orow = out + ((size_t)b * TT) * CGALL + cgt * CGT + cgi;

  const f32x4 al = alogit4[cgt * CGT + cgi];
  f32x4 a, d;
  a.x = 1.0f / (1.0f + __expf(-al.x));
  a.y = 1.0f / (1.0f + __expf(-al.y));
  a.z = 1.0f / (1.0f + __expf(-al.z));
  a.w = 1.0f / (1.0f + __expf(-al.w));
  d.x = 1.0f - a.x; d.y = 1.0f - a.y; d.z = 1.0f - a.z; d.w = 1.0f - a.w;
  const f32x4 d2 = d * d, d4 = d2 * d2;
  const f32x4 d8 = d4 * d4;

  // ---- own chunk loads, pre-scaled: ax[i] = a * x[t0+i] ----
  f32x4 ax[LCH];
#pragma unroll
  for (int i = 0; i < LCH; ++i) ax[i] = a * xr[(size_t)(t0 + i) * CGALL];

  // ---- wave-edge histories (redundant across lanes; 1 line per load) ----
  f32x4 Hf;  // fwd value at time t0w-1
  {
    int t = t0w - HALO;
    f32x4 c = xr[(size_t)(t < 0 ? 0 : t) * CGALL];
#pragma unroll
    for (int k = 1; k < HALO; ++k) {
      int tt = t0w - HALO + k;
      c = fma4(a, xr[(size_t)(tt < 0 ? 0 : tt) * CGALL], d * c);
    }
    Hf = c;
  }
  f32x4 Hb;  // bwd value at time t0w+TB
  {
    int t = t0w + TB + HALO - 1;
    f32x4 c = xr[(size_t)(t > TT - 1 ? TT - 1 : t) * CGALL];
#pragma unroll
    for (int k = 1; k < HALO; ++k) {
      int tt = t0w + TB + HALO - 1 - k;
      c = fma4(a, xr[(size_t)(tt > TT - 1 ? TT - 1 : tt) * CGALL], d * c);
    }
    Hb = c;
  }

  // ---- zero-init local ends ----
  f32x4 le = ax[0];   // fwd local end  = sum_k d^(7-k) ax[k]
  f32x4 ble = ax[0];  // bwd local end  = sum_k d^k     ax[k]
  {
    f32x4 p = d;
#pragma unroll
    for (int i = 1; i < LCH; ++i) {
      le = fma4(d, le, ax[i]);
      ble = fma4(p, ax[i], ble);
      p = p * d;
    }
  }

  const f32x4 vzero = {0.f, 0.f, 0.f, 0.f};

  // ---- fwd carry-in: Horner over 4 shuffle terms, history folded in ----
  f32x4 F;
  {
    const f32x4 s1 = shfl4(le, lane - 8);
    const f32x4 s2 = shfl4(le, lane - 16);
    const f32x4 s3 = shfl4(le, lane - 24);
    const f32x4 s4 = shfl4(le, lane - 32);
    const f32x4 t1 = (ch >= 1) ? s1 : Hf;
    const f32x4 t2 = (ch >= 2) ? s2 : ((ch == 1) ? Hf : vzero);
    const f32x4 t3 = (ch >= 3) ? s3 : ((ch == 2) ? Hf : vzero);
    const f32x4 t4 = (ch >= 4) ? s4 : ((ch == 3) ? Hf : vzero);
    F = fma4(d8, t4, t3);
    F = fma4(d8, F, t2);
    F = fma4(d8, F, t1);
  }

  // ---- bwd carry-in (mirror) ----
  f32x4 B;
  {
    const f32x4 s1 = shfl4(ble, lane + 8);
    const f32x4 s2 = shfl4(ble, lane + 16);
    const f32x4 s3 = shfl4(ble, lane + 24);
    const f32x4 s4 = shfl4(ble, lane + 32);
    const f32x4 t1 = (ch <= 6) ? s1 : Hb;
    const f32x4 t2 = (ch <= 5) ? s2 : ((ch == 6) ? Hb : vzero);
    const f32x4 t3 = (ch <= 4) ? s3 : ((ch == 5) ? Hb : vzero);
    const f32x4 t4 = (ch <= 3) ? s4 : ((ch == 4) ? Hb : vzero);
    B = fma4(d8, t4, t3);
    B = fma4(d8, B, t2);
    B = fma4(d8, B, t1);
  }

  // ---- pass 2: true scans + fused averaged store ----
  f32x4 fr[LCH];
  f32x4 c = F;
#pragma unroll
  for (int i = 0; i < LCH; ++i) {
    c = fma4(d, c, ax[i]);
    fr[i] = c;
  }
  c = B;
#pragma unroll
  for (int i = LCH - 1; i >= 0; --i) {
    c = fma4(d, c, ax[i]);
    const f32x4 s = fr[i] + c;
    f32x4 r;
    r.x = 0.5f * s.x; r.y = 0.5f * s.y; r.z = 0.5f * s.z; r.w = 0.5f * s.w;
    orow[(size_t)(t0 + i) * CGALL] = r;
  }
}

extern "C" void kernel_launch(void* const* d_in, const int* in_sizes, int n_in,
                              void* d_out, int out_size, void* d_ws,
                              size_t ws_size, hipStream_t stream) {
  const f32x4* x = (const f32x4*)d_in[0];
  const f32x4* alogit4 = (const f32x4*)d_in[1];
  f32x4* out = (f32x4*)d_out;

  const int grid = BB * NCGQ * NTB;  // 4096 blocks x 256 threads
  ema_bidir_kernel<<<grid, 256, 0, stream>>>(x, alogit4, out);
}

// Round 11
// 46.108 us; speedup vs baseline: 1.2056x; 1.2056x over previous
//
#include <hip/hip_runtime.h>

// TemporalDenoise: bidirectional per-channel EMA, averaged.
// R11 = R7 (barrier-free wave-private LDS tiles, global_load_lds staging,
// counted vmcnt, xi[] register save) with ONE lever: TB=64 (was 128).
//  - LDS tile 96 slots x 8 groups = 12 KB -> 13 blocks/CU (R7: 20KB -> 7).
//    ~1.9x co-resident waves to overlap stage/compute/store phases.
//  - Cost: halo read fraction 1.25x -> 1.5x, but halo reads are L2/L3-hot.
//  - Everything else identical to R7: 1-wave blocks, no __syncthreads,
//    vmcnt(2) covers all fwd-phase slots (in-order retire), vmcnt(0) before
//    bwd warm-up; source-side XOR swizzle (LDS dest linear); plain stores.
// HALO=16: 0.7^16 ~ 3.3e-3 decay, threshold 5.06e-2. Clamped staging makes
// t=0 / t=T-1 exact (EMA over repeated x[0] is x[0], matches ref init).

#define BB 32
#define TT 2048
#define CGALL 128              // f32x4 groups per (b,t) row (512 ch)
#define CGT 8                  // f32x4 groups per tile = 32 ch = 128B per t
#define NCGT (CGALL / CGT)     // 16
#define TB 64                  // output time steps per wave
#define HALO 16
#define SLOTS (TB + 2 * HALO)  // 96
#define LCH 8                  // time steps per thread
#define NTB (TT / TB)          // 32 time tiles
#define NTHREADS 64
#define STAGE_ITERS ((SLOTS * CGT) / NTHREADS)  // 12

typedef float f32x4 __attribute__((ext_vector_type(4)));
typedef __attribute__((address_space(3))) unsigned int lds_uint;
typedef const __attribute__((address_space(1))) unsigned int glob_uint;

static __device__ __forceinline__ void ema4(f32x4& c, const f32x4 v,
                                            const f32x4 a, const f32x4 d) {
  c.x = fmaf(a.x, v.x, d.x * c.x);
  c.y = fmaf(a.y, v.y, d.y * c.y);
  c.z = fmaf(a.z, v.z, d.z * c.z);
  c.w = fmaf(a.w, v.w, d.w * c.w);
}

// LDS element index for logical (slot s, group g).
static __device__ __forceinline__ int swz(int s, int g) {
  return s * CGT + (g ^ ((s >> 3) & 7));
}

__global__ __launch_bounds__(NTHREADS, 2) void ema_bidir_kernel(
    const f32x4* __restrict__ x, const f32x4* __restrict__ alogit4,
    f32x4* __restrict__ out) {
  __shared__ f32x4 tile[SLOTS * CGT];  // 12288 B -> 13 blocks/CU

  const int bid = blockIdx.x;
  const int cgt = bid & (NCGT - 1);        // channel tile (fastest; tb-stride
  const int tb = (bid >> 4) & (NTB - 1);   //  =16 -> tb-neighbors same XCD)
  const int b = bid >> 9;                  // batch

  const int tid = threadIdx.x;
  const int cgi = tid & (CGT - 1);  // 0..7 channel group
  const int ch = tid >> 3;          // 0..7 time chunk

  const int tile_t0 = tb * TB;
  const f32x4* xb = x + ((size_t)b * TT) * CGALL + cgt * CGT;
  f32x4* ob = out + ((size_t)b * TT) * CGALL + cgt * CGT;

  // ---- stage wave-private tile via global_load_lds ----
  // dest element tid + 64k = (slot s = (tid>>3)+8k, slot-group gp = tid&7);
  // s>>3 == k exactly (sb<8), so the source XOR is uniform per iteration:
  // gsrc = gp ^ (k&7); lanes still cover a contiguous 1KB line group.
  {
    const int sb = tid >> 3;
    const int gp = tid & 7;
#pragma unroll
    for (int k = 0; k < STAGE_ITERS; ++k) {
      const int s = sb + 8 * k;
      int t = tile_t0 - HALO + s;
      t = t < 0 ? 0 : (t > TT - 1 ? TT - 1 : t);
      const int gsrc = gp ^ (k & 7);
      const f32x4* src = xb + (size_t)t * CGALL + gsrc;
      __builtin_amdgcn_global_load_lds((glob_uint*)src,
                                       (lds_uint*)&tile[tid + k * NTHREADS],
                                       16, 0, 0);
    }
  }

  // sigmoid while loads fly
  const f32x4 al = alogit4[cgt * CGT + cgi];
  f32x4 a, d;
  a.x = 1.0f / (1.0f + __expf(-al.x));
  a.y = 1.0f / (1.0f + __expf(-al.y));
  a.z = 1.0f / (1.0f + __expf(-al.z));
  a.w = 1.0f / (1.0f + __expf(-al.w));
  d.x = 1.0f - a.x; d.y = 1.0f - a.y; d.z = 1.0f - a.z; d.w = 1.0f - a.w;

  const int s0 = HALO + ch * LCH;  // first main slot of this chunk

  // fwd pass touches slots <= HALO+TB-1 = 79 -> elements <= 639 -> loads
  // k=0..9 of 12; wait until 10 oldest done -> vmcnt(2).
  asm volatile("s_waitcnt vmcnt(2)" ::: "memory");
  __builtin_amdgcn_sched_barrier(0);

  // ---- forward: warm-up + main (save raw x into xi, results into fr) ----
  f32x4 cf = tile[swz(s0 - HALO, cgi)];
#pragma unroll
  for (int k = 1; k < HALO; ++k) {
    ema4(cf, tile[swz(s0 - HALO + k, cgi)], a, d);
  }
  f32x4 xi[LCH], fr[LCH];
#pragma unroll
  for (int i = 0; i < LCH; ++i) {
    xi[i] = tile[swz(s0 + i, cgi)];
    ema4(cf, xi[i], a, d);
    fr[i] = cf;
  }

  // remaining loads (slots 80..95): bwd warm-up territory
  asm volatile("s_waitcnt vmcnt(0)" ::: "memory");
  __builtin_amdgcn_sched_barrier(0);

  // ---- backward: warm-up from LDS, main from xi[], fused store ----
  f32x4 cb = tile[swz(s0 + LCH - 1 + HALO, cgi)];
#pragma unroll
  for (int k = 1; k < HALO; ++k) {
    ema4(cb, tile[swz(s0 + LCH - 1 + HALO - k, cgi)], a, d);
  }
#pragma unroll
  for (int i = LCH - 1; i >= 0; --i) {
    ema4(cb, xi[i], a, d);
    f32x4 r;
    r.x = 0.5f * (fr[i].x + cb.x);
    r.y = 0.5f * (fr[i].y + cb.y);
    r.z = 0.5f * (fr[i].z + cb.z);
    r.w = 0.5f * (fr[i].w + cb.w);
    ob[(size_t)(tile_t0 + ch * LCH + i) * CGALL + cgi] = r;
  }
}

extern "C" void kernel_launch(void* const* d_in, const int* in_sizes, int n_in,
                              void* d_out, int out_size, void* d_ws,
                              size_t ws_size, hipStream_t stream) {
  const f32x4* x = (const f32x4*)d_in[0];
  const f32x4* alogit4 = (const f32x4*)d_in[1];
  f32x4* out = (f32x4*)d_out;

  const int grid = BB * NCGT * NTB;  // 16384 blocks x 64 threads
  ema_bidir_kernel<<<grid, NTHREADS, 0, stream>>>(x, alogit4, out);
}